// Round 19
// baseline (103.150 us; speedup 1.0000x reference)
//
#include <hip/hip_runtime.h>

#define Bn 16
#define Sn 128
#define Hn 256
#define NLn 22
#define NSn 122

#define K2c 2.8853900817779268f   // 2*log2(e)
#define L2Ec 1.4426950408889634f  // log2(e)

__device__ __forceinline__ float fexp2(float x) { return __builtin_amdgcn_exp2f(x); }
__device__ __forceinline__ float frcp(float x) { return __builtin_amdgcn_rcpf(x); }

union F4 { float4 v; float f[4]; };

// ---------------------------------------------------------------------------
// A-update body: rL -> m -> em -> f -> g2.  1024 threads = h(256) x kq(4).
// Writes g2[b][h] directly.  use_alpha=0 for iteration 0.
// ---------------------------------------------------------------------------
__device__ __forceinline__ void A_body(const float* __restrict__ c_slot,
                                       const float* __restrict__ c_inte,
                                       const float* __restrict__ W_SF,
                                       const float* __restrict__ V_SF,
                                       const float* __restrict__ alphas,
                                       float* __restrict__ g2,
                                       int b, int use_alpha,
                                       float* rL, float* fLq, float* aL,
                                       float (*pt)[Hn]) {
  const int tid = threadIdx.x;
  const int h = tid & (Hn - 1);
  const int kq = tid >> 8;

  if (use_alpha) {
    if (tid < Sn) aL[tid] = alphas[b * Sn + tid];
    __syncthreads();
    float ps = 0.f;
    #pragma unroll 8
    for (int s = kq * 32; s < kq * 32 + 32; ++s)
      ps += c_slot[(size_t)(b * Sn + s) * Hn + h] * aL[s];
    pt[kq][h] = ps;
    __syncthreads();
    if (!kq)
      rL[h] = c_inte[b * Hn + h] +
              g2[b * Hn + h] * (pt[0][h] + pt[1][h] + pt[2][h] + pt[3][h]);
  } else {
    if (!kq) rL[h] = c_inte[b * Hn + h];
  }
  __syncthreads();

  // m = rL @ W_SF (4-way k-split)
  float pm = 0.f;
  #pragma unroll 8
  for (int k = kq * 64; k < kq * 64 + 64; ++k)
    pm += rL[k] * W_SF[(size_t)k * Hn + h];
  __syncthreads();               // protect pt from rs-phase reads
  pt[kq][h] = pm;
  __syncthreads();
  const float m = pt[0][h] + pt[1][h] + pt[2][h] + pt[3][h];
  const float em = fexp2(fminf(fmaxf(K2c * m, -60.f), 60.f));

  // f partial: 32 s per kq
  float pr = 0.f;
  #pragma unroll 8
  for (int s = kq * 32; s < kq * 32 + 32; ++s) {
    float zc = fminf(fmaxf(K2c * c_slot[(size_t)(b * Sn + s) * Hn + h], -60.f), 60.f);
    pr += frcp(fmaf(fexp2(zc), em, 1.f));
  }
  __syncthreads();               // all m-reads of pt complete
  pt[kq][h] = pr;
  __syncthreads();
  if (!kq) fLq[h] = (float)Sn - 2.f * (pt[0][h] + pt[1][h] + pt[2][h] + pt[3][h]);
  __syncthreads();

  // g2 = fLq @ V_SF (4-way k-split)
  float pg = 0.f;
  #pragma unroll 8
  for (int k = kq * 64; k < kq * 64 + 64; ++k)
    pg += fLq[k] * V_SF[(size_t)k * Hn + h];
  __syncthreads();
  pt[kq][h] = pg;
  __syncthreads();
  if (!kq)
    g2[b * Hn + h] = pt[0][h] + pt[1][h] + pt[2][h] + pt[3][h];
}

// ---------------------------------------------------------------------------
// k_hfA: blocks 0..255: hf -> ZT (8 rows each, j-contiguous exp2(K2*hf)).
//        blocks 256..271: A-update for iteration 0 (no alphas) -> g2.
// ---------------------------------------------------------------------------
__global__ __launch_bounds__(1024) void k_hfA(const float* __restrict__ hp,
                                              const float* __restrict__ V2w,
                                              const float* __restrict__ V2b,
                                              const float* __restrict__ c_slot,
                                              const float* __restrict__ c_inte,
                                              const float* __restrict__ W_SF,
                                              const float* __restrict__ V_SF,
                                              float* __restrict__ ZT,
                                              float* __restrict__ g2) {
  __shared__ float xT[Hn][8];
  __shared__ float pp[3][Hn][8];
  __shared__ float rL[Hn];
  __shared__ float fLq[Hn];
  __shared__ float aL[Sn];
  __shared__ float pt[4][Hn];
  const int tid = threadIdx.x;
  const int blk = blockIdx.x;

  if (blk >= 256) {              // A-update, iteration 0
    A_body(c_slot, c_inte, W_SF, V_SF, nullptr, g2, blk - 256, 0,
           rL, fLq, aL, pt);
    return;
  }

  const int r0 = blk * 8;
  const int b = r0 >> 7;
  const int j0 = r0 & (Sn - 1);
  const int h = tid & (Hn - 1);
  const int kh = tid >> 8;       // 0..3
  xT[h][kh * 2]     = hp[(size_t)(r0 + kh * 2) * Hn + h];
  xT[h][kh * 2 + 1] = hp[(size_t)(r0 + kh * 2 + 1) * Hn + h];
  __syncthreads();
  float acc[8] = {0.f, 0.f, 0.f, 0.f, 0.f, 0.f, 0.f, 0.f};
  #pragma unroll 8
  for (int k = kh * 64; k < kh * 64 + 64; ++k) {
    const float v = V2w[(size_t)k * Hn + h];
    F4 xa, xb;
    xa.v = *(const float4*)&xT[k][0];
    xb.v = *(const float4*)&xT[k][4];
    acc[0] += xa.f[0] * v; acc[1] += xa.f[1] * v;
    acc[2] += xa.f[2] * v; acc[3] += xa.f[3] * v;
    acc[4] += xb.f[0] * v; acc[5] += xb.f[1] * v;
    acc[6] += xb.f[2] * v; acc[7] += xb.f[3] * v;
  }
  if (kh) {
    F4 s0, s1;
    s0.f[0] = acc[0]; s0.f[1] = acc[1]; s0.f[2] = acc[2]; s0.f[3] = acc[3];
    s1.f[0] = acc[4]; s1.f[1] = acc[5]; s1.f[2] = acc[6]; s1.f[3] = acc[7];
    *(float4*)&pp[kh - 1][h][0] = s0.v;
    *(float4*)&pp[kh - 1][h][4] = s1.v;
  }
  __syncthreads();
  if (!kh) {
    const float bj = V2b[h];
    F4 o0, o1;
    #pragma unroll
    for (int i = 0; i < 8; ++i) {
      float z = K2c * (acc[i] + pp[0][h][i] + pp[1][h][i] + pp[2][h][i] + bj);
      z = fminf(fmaxf(z, -60.f), 60.f);
      if (i < 4) o0.f[i] = fexp2(z); else o1.f[i - 4] = fexp2(z);
    }
    *(float4*)&ZT[((size_t)b * Hn + h) * Sn + j0] = o0.v;
    *(float4*)&ZT[((size_t)b * Hn + h) * Sn + j0 + 4] = o1.v;
  }
}

// ---------------------------------------------------------------------------
// k_A: iterations 1,2. 16 blocks (one per b) x 1024 threads. Writes g2.
// ---------------------------------------------------------------------------
__global__ __launch_bounds__(1024) void k_A(const float* __restrict__ c_slot,
                                            const float* __restrict__ c_inte,
                                            const float* __restrict__ W_SF,
                                            const float* __restrict__ V_SF,
                                            const float* __restrict__ alphas,
                                            float* __restrict__ g2) {
  __shared__ float rL[Hn];
  __shared__ float fLq[Hn];
  __shared__ float aL[Sn];
  __shared__ float pt[4][Hn];
  A_body(c_slot, c_inte, W_SF, V_SF, alphas, g2, blockIdx.x, 1,
         rL, fLq, aL, pt);
}

// ---------------------------------------------------------------------------
// k_C: blocks 0..255: scores (b = blk & 15 -> T1 XCD mapping; paired-rcp).
//      blocks 256..511 (only when do_slot, final iteration): slot head,
//      8 rows each — depends only on g2, fills the second block-slot per CU
//      (scores alone = 1 block/CU = 50% occupancy; 512 = exact capacity).
// ---------------------------------------------------------------------------
__global__ __launch_bounds__(1024) void k_C(const float* __restrict__ c_slot,
                                            const float* __restrict__ V1,
                                            const float* __restrict__ g2,
                                            const float* __restrict__ ZT,
                                            const float* __restrict__ wid,
                                            float* __restrict__ alphas,
                                            const float* __restrict__ hp,
                                            const float* __restrict__ Ws,
                                            float* __restrict__ outS) {
  __shared__ union Shm {
    struct {
      float bufA[Hn][8];
      float bufB[Hn][8];
      union { float pp[3][Hn][8]; float red[7][8][Sn]; } u;
      float sc8[8][Sn];
      float wL[Hn];
    } c;
    struct {
      float bufA[Hn][8];
      float bufB[Hn][8];
      float red[7][8][Sn];
    } s;
  } shm;

  const int tid = threadIdx.x;
  const int blk = blockIdx.x;

  if (blk >= 256) {
    // ---------------- slot head: outS rows r0..r0+7 ----------------
    const int sb = blk - 256;
    const int r0 = sb * 8;
    const int b2 = r0 >> 7;
    const int h = tid & (Hn - 1);
    const int q4 = tid >> 8;     // 0..3
    const float gv = g2[b2 * Hn + h];
    #pragma unroll
    for (int i = 0; i < 2; ++i) {
      const int row = q4 * 2 + i;
      shm.s.bufA[h][row] = hp[(size_t)(r0 + row) * Hn + h];
      shm.s.bufB[h][row] = gv * c_slot[(size_t)(r0 + row) * Hn + h];
    }
    __syncthreads();
    const int jc = tid & 127;
    const int k8 = tid >> 7;     // 0..7, 64 k each over 512
    float acc[8] = {0.f, 0.f, 0.f, 0.f, 0.f, 0.f, 0.f, 0.f};
    if (jc < NSn) {
      const float (*xb)[8] = (k8 < 4) ? shm.s.bufA : shm.s.bufB;
      const int kg0 = k8 * 64;
      const int koff = (k8 < 4) ? 0 : 256;
      #pragma unroll 8
      for (int u = 0; u < 64; ++u) {
        const float v = Ws[(size_t)(kg0 + u) * NSn + jc];
        F4 xa, xb4;
        xa.v = *(const float4*)&xb[kg0 - koff + u][0];
        xb4.v = *(const float4*)&xb[kg0 - koff + u][4];
        acc[0] += xa.f[0] * v; acc[1] += xa.f[1] * v;
        acc[2] += xa.f[2] * v; acc[3] += xa.f[3] * v;
        acc[4] += xb4.f[0] * v; acc[5] += xb4.f[1] * v;
        acc[6] += xb4.f[2] * v; acc[7] += xb4.f[3] * v;
      }
    }
    if (k8) {
      #pragma unroll
      for (int i = 0; i < 8; ++i) shm.s.red[k8 - 1][i][jc] = acc[i];
    }
    __syncthreads();
    if (!k8 && jc < NSn) {
      #pragma unroll
      for (int i = 0; i < 8; ++i) {
        float tot = acc[i];
        #pragma unroll
        for (int r = 0; r < 7; ++r) tot += shm.s.red[r][i][jc];
        outS[(size_t)(r0 + i) * NSn + jc] = tot;
      }
    }
    return;
  }

  // ---------------- scores ----------------
  const int b = blk & 15;          // T1: same-b blocks -> same XCD
  const int i0 = (blk >> 4) * 8;
  const int h = tid & (Hn - 1);
  const int kq = tid >> 8;         // 0..3

  // phase1: 2 rows per thread
  {
    const float gv = g2[b * Hn + h];
    const int ii = kq * 2;
    shm.c.bufA[h][ii]     = gv * c_slot[(size_t)(b * Sn + i0 + ii) * Hn + h];
    shm.c.bufA[h][ii + 1] = gv * c_slot[(size_t)(b * Sn + i0 + ii + 1) * Hn + h];
    if (tid < Hn) shm.c.wL[tid] = wid[tid];
  }
  __syncthreads();

  // phase2: sf = x @ V1 (4-way kq split) -> Y
  {
    float acc[8] = {0.f, 0.f, 0.f, 0.f, 0.f, 0.f, 0.f, 0.f};
    #pragma unroll 8
    for (int k = kq * 64; k < kq * 64 + 64; ++k) {
      const float v = V1[(size_t)k * Hn + h];
      F4 xa, xb;
      xa.v = *(const float4*)&shm.c.bufA[k][0];
      xb.v = *(const float4*)&shm.c.bufA[k][4];
      acc[0] += xa.f[0] * v; acc[1] += xa.f[1] * v;
      acc[2] += xa.f[2] * v; acc[3] += xa.f[3] * v;
      acc[4] += xb.f[0] * v; acc[5] += xb.f[1] * v;
      acc[6] += xb.f[2] * v; acc[7] += xb.f[3] * v;
    }
    if (kq) {
      F4 s0, s1;
      s0.f[0] = acc[0]; s0.f[1] = acc[1]; s0.f[2] = acc[2]; s0.f[3] = acc[3];
      s1.f[0] = acc[4]; s1.f[1] = acc[5]; s1.f[2] = acc[6]; s1.f[3] = acc[7];
      *(float4*)&shm.c.u.pp[kq - 1][h][0] = s0.v;
      *(float4*)&shm.c.u.pp[kq - 1][h][4] = s1.v;
    }
    __syncthreads();
    if (!kq) {
      #pragma unroll
      for (int i = 0; i < 8; ++i) {
        float z = K2c * (acc[i] + shm.c.u.pp[0][h][i] + shm.c.u.pp[1][h][i] +
                         shm.c.u.pp[2][h][i]);
        z = fminf(fmaxf(z, -60.f), 60.f);
        shm.c.bufB[h][i] = fexp2(z);
      }
    }
  }
  __syncthreads();

  // phase3: paired-rcp einsum (lane = j), 16 hh-pairs per thread
  const int j = tid & (Sn - 1);
  const int hq = tid >> 7;         // 0..7
  float a8[8] = {0.f, 0.f, 0.f, 0.f, 0.f, 0.f, 0.f, 0.f};
  const float* zp = ZT + ((size_t)b * Hn + hq * 32) * Sn + j;
  #pragma unroll 2
  for (int hh = 0; hh < 32; hh += 2) {
    const float z1 = zp[(size_t)hh * Sn];
    const float z2 = zp[(size_t)(hh + 1) * Sn];
    const float w1 = shm.c.wL[hq * 32 + hh];
    const float w2 = shm.c.wL[hq * 32 + hh + 1];
    F4 ya1, yb1, ya2, yb2;
    ya1.v = *(const float4*)&shm.c.bufB[hq * 32 + hh][0];
    yb1.v = *(const float4*)&shm.c.bufB[hq * 32 + hh][4];
    ya2.v = *(const float4*)&shm.c.bufB[hq * 32 + hh + 1][0];
    yb2.v = *(const float4*)&shm.c.bufB[hq * 32 + hh + 1][4];
    #pragma unroll
    for (int i = 0; i < 4; ++i) {
      {
        const float A = fmaf(ya1.f[i], z1, 1.f);
        const float B = fmaf(ya2.f[i], z2, 1.f);
        const float N = fmaf(w1, B, w2 * A);
        a8[i] = fmaf(N, frcp(A * B), a8[i]);
      }
      {
        const float A = fmaf(yb1.f[i], z1, 1.f);
        const float B = fmaf(yb2.f[i], z2, 1.f);
        const float N = fmaf(w1, B, w2 * A);
        a8[4 + i] = fmaf(N, frcp(A * B), a8[4 + i]);
      }
    }
  }
  if (hq) {
    #pragma unroll
    for (int i = 0; i < 8; ++i) shm.c.u.red[hq - 1][i][j] = a8[i];
  }
  __syncthreads();
  if (!hq) {
    #pragma unroll
    for (int i = 0; i < 8; ++i) {
      float tot = a8[i];
      #pragma unroll
      for (int r = 0; r < 7; ++r) tot += shm.c.u.red[r][i][j];
      shm.c.sc8[i][j] = -2.f * L2Ec * tot;   // log2-domain score (const dropped)
    }
  }
  __syncthreads();

  // phase4: softmax, 8 rows x 32 lanes
  if (tid < 256) {
    const int row = tid >> 5;
    const int l5 = tid & 31;
    const float v0 = shm.c.sc8[row][l5];
    const float v1 = shm.c.sc8[row][l5 + 32];
    const float v2 = shm.c.sc8[row][l5 + 64];
    const float v3 = shm.c.sc8[row][l5 + 96];
    float mx = fmaxf(fmaxf(v0, v1), fmaxf(v2, v3));
    #pragma unroll
    for (int o = 16; o >= 1; o >>= 1) mx = fmaxf(mx, __shfl_xor(mx, o, 32));
    float sm = fexp2(v0 - mx) + fexp2(v1 - mx) + fexp2(v2 - mx) + fexp2(v3 - mx);
    #pragma unroll
    for (int o = 16; o >= 1; o >>= 1) sm += __shfl_xor(sm, o, 32);
    if (l5 == 0) {
      const int ig = i0 + row;
      alphas[b * Sn + ig] = fexp2(shm.c.sc8[row][ig] - mx) * frcp(sm);
    }
  }
}

// ---------------------------------------------------------------------------
// k_int: intent head only. 16 blocks x 512 threads.
// ---------------------------------------------------------------------------
__global__ __launch_bounds__(512) void k_int(const float* __restrict__ hp,
                                             const float* __restrict__ c_slot,
                                             const float* __restrict__ c_inte,
                                             const float* __restrict__ g2,
                                             const float* __restrict__ alphas,
                                             const float* __restrict__ Wi,
                                             float* __restrict__ outI) {
  __shared__ float aL[Sn];
  __shared__ float cv[2 * Hn];
  __shared__ float ptA[2][Hn];
  __shared__ float ip[NLn][16];
  const int b = blockIdx.x;
  const int tid = threadIdx.x;
  if (tid < Sn) aL[tid] = alphas[b * Sn + tid];
  __syncthreads();
  const int h = tid & (Hn - 1);
  const int k2 = tid >> 8;
  float ps = 0.f;
  #pragma unroll 8
  for (int s = k2 * 64; s < k2 * 64 + 64; ++s)
    ps += c_slot[(size_t)(b * Sn + s) * Hn + h] * aL[s];
  ptA[k2][h] = ps;
  __syncthreads();
  if (!k2) {
    cv[h] = c_inte[b * Hn + h] + g2[b * Hn + h] * (ptA[0][h] + ptA[1][h]);
    cv[Hn + h] = hp[(size_t)(b * Sn + Sn - 1) * Hn + h];
  }
  __syncthreads();
  if (tid < NLn * 16) {
    const int l = tid >> 4, c = tid & 15;
    float p = 0.f;
    #pragma unroll
    for (int k = c * 32; k < c * 32 + 32; ++k) p += cv[k] * Wi[k * NLn + l];
    ip[l][c] = p;
  }
  __syncthreads();
  if (tid < NLn) {
    float t = 0.f;
    #pragma unroll
    for (int c = 0; c < 16; ++c) t += ip[tid][c];
    outI[b * NLn + tid] = t;
  }
}

// ---------------------------------------------------------------------------
extern "C" void kernel_launch(void* const* d_in, const int* in_sizes, int n_in,
                              void* d_out, int out_size, void* d_ws, size_t ws_size,
                              hipStream_t stream) {
  const float* hp     = (const float*)d_in[0];
  const float* c_slot = (const float*)d_in[1];
  const float* c_inte = (const float*)d_in[2];
  const float* W_SF   = (const float*)d_in[3];
  const float* V_SF   = (const float*)d_in[4];
  const float* V1     = (const float*)d_in[5];
  const float* V2w    = (const float*)d_in[6];
  const float* V2b    = (const float*)d_in[7];
  const float* wid    = (const float*)d_in[8];
  const float* Wi     = (const float*)d_in[9];
  const float* Ws     = (const float*)d_in[10];
  float* outS = (float*)d_out;                   // B*S*NS
  float* outI = (float*)d_out + Bn * Sn * NSn;   // B*NL

  float* ws = (float*)d_ws;
  float* ZT     = ws;                       // B*H*S (j-contig)
  float* g2     = ZT + (size_t)Bn * Sn * Hn;
  float* alphas = g2 + Bn * Hn;

  // hf + A(it=0) fused
  hipLaunchKernelGGL(k_hfA, dim3(256 + Bn), dim3(1024), 0, stream,
                     hp, V2w, V2b, c_slot, c_inte, W_SF, V_SF, ZT, g2);
  for (int it = 0; it < 3; ++it) {
    if (it) hipLaunchKernelGGL(k_A, dim3(Bn), dim3(1024), 0, stream,
                               c_slot, c_inte, W_SF, V_SF, alphas, g2);
    // final iteration: +256 slot-head blocks (depend only on g2) fill the
    // second block-slot per CU that scores alone leave empty.
    hipLaunchKernelGGL(k_C, dim3(it == 2 ? 512 : 256), dim3(1024), 0, stream,
                       c_slot, V1, g2, ZT, wid, alphas, hp, Ws, outS);
  }
  hipLaunchKernelGGL(k_int, dim3(Bn), dim3(512), 0, stream,
                     hp, c_slot, c_inte, g2, alphas, Wi, outI);
}

// Round 20
// 94.207 us; speedup vs baseline: 1.0949x; 1.0949x over previous
//
#include <hip/hip_runtime.h>

#define Bn 16
#define Sn 128
#define Hn 256
#define NLn 22
#define NSn 122

#define K2c 2.8853900817779268f   // 2*log2(e)
#define L2Ec 1.4426950408889634f  // log2(e)

__device__ __forceinline__ float fexp2(float x) { return __builtin_amdgcn_exp2f(x); }
__device__ __forceinline__ float frcp(float x) { return __builtin_amdgcn_rcpf(x); }

union F4 { float4 v; float f[4]; };

// ---------------------------------------------------------------------------
// A-update body: rL -> m -> em -> f -> g2.  1024 threads = h(256) x kq(4).
// Writes g2[b][h] directly.  use_alpha=0 for iteration 0.
// ---------------------------------------------------------------------------
__device__ __forceinline__ void A_body(const float* __restrict__ c_slot,
                                       const float* __restrict__ c_inte,
                                       const float* __restrict__ W_SF,
                                       const float* __restrict__ V_SF,
                                       const float* __restrict__ alphas,
                                       float* __restrict__ g2,
                                       int b, int use_alpha,
                                       float* rL, float* fLq, float* aL,
                                       float (*pt)[Hn]) {
  const int tid = threadIdx.x;
  const int h = tid & (Hn - 1);
  const int kq = tid >> 8;

  if (use_alpha) {
    if (tid < Sn) aL[tid] = alphas[b * Sn + tid];
    __syncthreads();
    float ps = 0.f;
    #pragma unroll 8
    for (int s = kq * 32; s < kq * 32 + 32; ++s)
      ps += c_slot[(size_t)(b * Sn + s) * Hn + h] * aL[s];
    pt[kq][h] = ps;
    __syncthreads();
    if (!kq)
      rL[h] = c_inte[b * Hn + h] +
              g2[b * Hn + h] * (pt[0][h] + pt[1][h] + pt[2][h] + pt[3][h]);
  } else {
    if (!kq) rL[h] = c_inte[b * Hn + h];
  }
  __syncthreads();

  // m = rL @ W_SF (4-way k-split)
  float pm = 0.f;
  #pragma unroll 8
  for (int k = kq * 64; k < kq * 64 + 64; ++k)
    pm += rL[k] * W_SF[(size_t)k * Hn + h];
  __syncthreads();               // protect pt from rs-phase reads
  pt[kq][h] = pm;
  __syncthreads();
  const float m = pt[0][h] + pt[1][h] + pt[2][h] + pt[3][h];
  const float em = fexp2(fminf(fmaxf(K2c * m, -60.f), 60.f));

  // f partial: 32 s per kq
  float pr = 0.f;
  #pragma unroll 8
  for (int s = kq * 32; s < kq * 32 + 32; ++s) {
    float zc = fminf(fmaxf(K2c * c_slot[(size_t)(b * Sn + s) * Hn + h], -60.f), 60.f);
    pr += frcp(fmaf(fexp2(zc), em, 1.f));
  }
  __syncthreads();               // all m-reads of pt complete
  pt[kq][h] = pr;
  __syncthreads();
  if (!kq) fLq[h] = (float)Sn - 2.f * (pt[0][h] + pt[1][h] + pt[2][h] + pt[3][h]);
  __syncthreads();

  // g2 = fLq @ V_SF (4-way k-split)
  float pg = 0.f;
  #pragma unroll 8
  for (int k = kq * 64; k < kq * 64 + 64; ++k)
    pg += fLq[k] * V_SF[(size_t)k * Hn + h];
  __syncthreads();
  pt[kq][h] = pg;
  __syncthreads();
  if (!kq)
    g2[b * Hn + h] = pt[0][h] + pt[1][h] + pt[2][h] + pt[3][h];
}

// ---------------------------------------------------------------------------
// k_hfA: blocks 0..255: hf -> ZT (8 rows each, j-contiguous exp2(K2*hf)).
//        blocks 256..271: A-update for iteration 0 (no alphas) -> g2.
// ---------------------------------------------------------------------------
__global__ __launch_bounds__(1024) void k_hfA(const float* __restrict__ hp,
                                              const float* __restrict__ V2w,
                                              const float* __restrict__ V2b,
                                              const float* __restrict__ c_slot,
                                              const float* __restrict__ c_inte,
                                              const float* __restrict__ W_SF,
                                              const float* __restrict__ V_SF,
                                              float* __restrict__ ZT,
                                              float* __restrict__ g2) {
  __shared__ float xT[Hn][8];
  __shared__ float pp[3][Hn][8];
  __shared__ float rL[Hn];
  __shared__ float fLq[Hn];
  __shared__ float aL[Sn];
  __shared__ float pt[4][Hn];
  const int tid = threadIdx.x;
  const int blk = blockIdx.x;

  if (blk >= 256) {              // A-update, iteration 0
    A_body(c_slot, c_inte, W_SF, V_SF, nullptr, g2, blk - 256, 0,
           rL, fLq, aL, pt);
    return;
  }

  const int r0 = blk * 8;
  const int b = r0 >> 7;
  const int j0 = r0 & (Sn - 1);
  const int h = tid & (Hn - 1);
  const int kh = tid >> 8;       // 0..3
  xT[h][kh * 2]     = hp[(size_t)(r0 + kh * 2) * Hn + h];
  xT[h][kh * 2 + 1] = hp[(size_t)(r0 + kh * 2 + 1) * Hn + h];
  __syncthreads();
  float acc[8] = {0.f, 0.f, 0.f, 0.f, 0.f, 0.f, 0.f, 0.f};
  #pragma unroll 8
  for (int k = kh * 64; k < kh * 64 + 64; ++k) {
    const float v = V2w[(size_t)k * Hn + h];
    F4 xa, xb;
    xa.v = *(const float4*)&xT[k][0];
    xb.v = *(const float4*)&xT[k][4];
    acc[0] += xa.f[0] * v; acc[1] += xa.f[1] * v;
    acc[2] += xa.f[2] * v; acc[3] += xa.f[3] * v;
    acc[4] += xb.f[0] * v; acc[5] += xb.f[1] * v;
    acc[6] += xb.f[2] * v; acc[7] += xb.f[3] * v;
  }
  if (kh) {
    F4 s0, s1;
    s0.f[0] = acc[0]; s0.f[1] = acc[1]; s0.f[2] = acc[2]; s0.f[3] = acc[3];
    s1.f[0] = acc[4]; s1.f[1] = acc[5]; s1.f[2] = acc[6]; s1.f[3] = acc[7];
    *(float4*)&pp[kh - 1][h][0] = s0.v;
    *(float4*)&pp[kh - 1][h][4] = s1.v;
  }
  __syncthreads();
  if (!kh) {
    const float bj = V2b[h];
    F4 o0, o1;
    #pragma unroll
    for (int i = 0; i < 8; ++i) {
      float z = K2c * (acc[i] + pp[0][h][i] + pp[1][h][i] + pp[2][h][i] + bj);
      z = fminf(fmaxf(z, -60.f), 60.f);
      if (i < 4) o0.f[i] = fexp2(z); else o1.f[i - 4] = fexp2(z);
    }
    *(float4*)&ZT[((size_t)b * Hn + h) * Sn + j0] = o0.v;
    *(float4*)&ZT[((size_t)b * Hn + h) * Sn + j0 + 4] = o1.v;
  }
}

// ---------------------------------------------------------------------------
// k_A: iterations 1,2. 16 blocks (one per b) x 1024 threads. Writes g2.
// ---------------------------------------------------------------------------
__global__ __launch_bounds__(1024) void k_A(const float* __restrict__ c_slot,
                                            const float* __restrict__ c_inte,
                                            const float* __restrict__ W_SF,
                                            const float* __restrict__ V_SF,
                                            const float* __restrict__ alphas,
                                            float* __restrict__ g2) {
  __shared__ float rL[Hn];
  __shared__ float fLq[Hn];
  __shared__ float aL[Sn];
  __shared__ float pt[4][Hn];
  A_body(c_slot, c_inte, W_SF, V_SF, alphas, g2, blockIdx.x, 1,
         rL, fLq, aL, pt);
}

// ---------------------------------------------------------------------------
// k_C: scores. 256 blocks = (b, 8-row group), 1024 threads, ~49KB LDS.
// T1 XCD mapping: b = blk & 15 (same-b blocks share an XCD L2).
// Phase3 uses PAIRED-RCP: w1/(1+t1)+w2/(1+t2) =
//   [w1(1+t2)+w2(1+t1)] * rcp((1+t1)(1+t2))  — halves trans-pipe ops.
// ---------------------------------------------------------------------------
__global__ __launch_bounds__(1024) void k_C(const float* __restrict__ c_slot,
                                            const float* __restrict__ V1,
                                            const float* __restrict__ g2,
                                            const float* __restrict__ ZT,
                                            const float* __restrict__ wid,
                                            float* __restrict__ alphas) {
  __shared__ float bufA[Hn][8];    // xT
  __shared__ float bufB[Hn][8];    // YT
  __shared__ union {
    float pp[3][Hn][8];            // phase2 partials (24KB)
    float red[7][8][Sn];           // phase3 partials (28KB)
  } u;
  __shared__ float sc8[8][Sn];
  __shared__ float wL[Hn];

  const int tid = threadIdx.x;
  const int blk = blockIdx.x;
  const int b = blk & 15;          // T1: same-b blocks -> same XCD
  const int i0 = (blk >> 4) * 8;
  const int h = tid & (Hn - 1);
  const int kq = tid >> 8;         // 0..3

  // phase1: 2 rows per thread
  {
    const float gv = g2[b * Hn + h];
    const int ii = kq * 2;
    bufA[h][ii]     = gv * c_slot[(size_t)(b * Sn + i0 + ii) * Hn + h];
    bufA[h][ii + 1] = gv * c_slot[(size_t)(b * Sn + i0 + ii + 1) * Hn + h];
    if (tid < Hn) wL[tid] = wid[tid];
  }
  __syncthreads();

  // phase2: sf = x @ V1 (4-way kq split) -> Y
  {
    float acc[8] = {0.f, 0.f, 0.f, 0.f, 0.f, 0.f, 0.f, 0.f};
    #pragma unroll 8
    for (int k = kq * 64; k < kq * 64 + 64; ++k) {
      const float v = V1[(size_t)k * Hn + h];
      F4 xa, xb;
      xa.v = *(const float4*)&bufA[k][0];
      xb.v = *(const float4*)&bufA[k][4];
      acc[0] += xa.f[0] * v; acc[1] += xa.f[1] * v;
      acc[2] += xa.f[2] * v; acc[3] += xa.f[3] * v;
      acc[4] += xb.f[0] * v; acc[5] += xb.f[1] * v;
      acc[6] += xb.f[2] * v; acc[7] += xb.f[3] * v;
    }
    if (kq) {
      F4 s0, s1;
      s0.f[0] = acc[0]; s0.f[1] = acc[1]; s0.f[2] = acc[2]; s0.f[3] = acc[3];
      s1.f[0] = acc[4]; s1.f[1] = acc[5]; s1.f[2] = acc[6]; s1.f[3] = acc[7];
      *(float4*)&u.pp[kq - 1][h][0] = s0.v;
      *(float4*)&u.pp[kq - 1][h][4] = s1.v;
    }
    __syncthreads();
    if (!kq) {
      #pragma unroll
      for (int i = 0; i < 8; ++i) {
        float z = K2c * (acc[i] + u.pp[0][h][i] + u.pp[1][h][i] + u.pp[2][h][i]);
        z = fminf(fmaxf(z, -60.f), 60.f);
        bufB[h][i] = fexp2(z);
      }
    }
  }
  __syncthreads();

  // phase3: paired-rcp einsum (lane = j), 16 hh-pairs per thread
  const int j = tid & (Sn - 1);
  const int hq = tid >> 7;         // 0..7
  float a8[8] = {0.f, 0.f, 0.f, 0.f, 0.f, 0.f, 0.f, 0.f};
  const float* zp = ZT + ((size_t)b * Hn + hq * 32) * Sn + j;
  #pragma unroll 2
  for (int hh = 0; hh < 32; hh += 2) {
    const float z1 = zp[(size_t)hh * Sn];
    const float z2 = zp[(size_t)(hh + 1) * Sn];
    const float w1 = wL[hq * 32 + hh];
    const float w2 = wL[hq * 32 + hh + 1];
    F4 ya1, yb1, ya2, yb2;
    ya1.v = *(const float4*)&bufB[hq * 32 + hh][0];
    yb1.v = *(const float4*)&bufB[hq * 32 + hh][4];
    ya2.v = *(const float4*)&bufB[hq * 32 + hh + 1][0];
    yb2.v = *(const float4*)&bufB[hq * 32 + hh + 1][4];
    #pragma unroll
    for (int i = 0; i < 4; ++i) {
      {
        const float A = fmaf(ya1.f[i], z1, 1.f);
        const float B = fmaf(ya2.f[i], z2, 1.f);
        const float N = fmaf(w1, B, w2 * A);
        a8[i] = fmaf(N, frcp(A * B), a8[i]);
      }
      {
        const float A = fmaf(yb1.f[i], z1, 1.f);
        const float B = fmaf(yb2.f[i], z2, 1.f);
        const float N = fmaf(w1, B, w2 * A);
        a8[4 + i] = fmaf(N, frcp(A * B), a8[4 + i]);
      }
    }
  }
  if (hq) {
    #pragma unroll
    for (int i = 0; i < 8; ++i) u.red[hq - 1][i][j] = a8[i];
  }
  __syncthreads();
  if (!hq) {
    #pragma unroll
    for (int i = 0; i < 8; ++i) {
      float tot = a8[i];
      #pragma unroll
      for (int r = 0; r < 7; ++r) tot += u.red[r][i][j];
      sc8[i][j] = -2.f * L2Ec * tot;   // log2-domain score (const dropped)
    }
  }
  __syncthreads();

  // phase4: softmax, 8 rows x 32 lanes
  if (tid < 256) {
    const int row = tid >> 5;
    const int l5 = tid & 31;
    const float v0 = sc8[row][l5];
    const float v1 = sc8[row][l5 + 32];
    const float v2 = sc8[row][l5 + 64];
    const float v3 = sc8[row][l5 + 96];
    float mx = fmaxf(fmaxf(v0, v1), fmaxf(v2, v3));
    #pragma unroll
    for (int o = 16; o >= 1; o >>= 1) mx = fmaxf(mx, __shfl_xor(mx, o, 32));
    float sm = fexp2(v0 - mx) + fexp2(v1 - mx) + fexp2(v2 - mx) + fexp2(v3 - mx);
    #pragma unroll
    for (int o = 16; o >= 1; o >>= 1) sm += __shfl_xor(sm, o, 32);
    if (l5 == 0) {
      const int ig = i0 + row;
      alphas[b * Sn + ig] = fexp2(sc8[row][ig] - mx) * frcp(sm);
    }
  }
}

// ---------------------------------------------------------------------------
// k_out: 256 blocks x 512. All blocks: slot head (8 rows). Blocks 0..15 also
// do the intent head afterwards (disjoint LDS arrays).
// ---------------------------------------------------------------------------
__global__ __launch_bounds__(512) void k_out(const float* __restrict__ hp,
                                             const float* __restrict__ c_slot,
                                             const float* __restrict__ c_inte,
                                             const float* __restrict__ g2,
                                             const float* __restrict__ alphas,
                                             const float* __restrict__ Wi,
                                             const float* __restrict__ Ws,
                                             float* __restrict__ outS,
                                             float* __restrict__ outI) {
  __shared__ float bufA[Hn][8];
  __shared__ float bufB[Hn][8];
  __shared__ float red[3][8][Sn];
  __shared__ float aL[Sn];
  __shared__ float cv[2 * Hn];
  __shared__ float ptA[2][Hn];
  __shared__ float ip[NLn][16];
  const int tid = threadIdx.x;
  const int blk = blockIdx.x;
  const int r0 = blk * 8;
  const int b2 = r0 >> 7;

  if (tid < Hn) {
    #pragma unroll
    for (int i = 0; i < 8; ++i) bufA[tid][i] = hp[(size_t)(r0 + i) * Hn + tid];
  } else {
    const int t = tid - Hn;
    const float gv = g2[b2 * Hn + t];
    #pragma unroll
    for (int i = 0; i < 8; ++i)
      bufB[t][i] = gv * c_slot[(size_t)(r0 + i) * Hn + t];
  }
  __syncthreads();
  const int jc = tid & 127;
  const int kq = tid >> 7;
  float acc[8] = {0.f, 0.f, 0.f, 0.f, 0.f, 0.f, 0.f, 0.f};
  if (jc < NSn) {
    const float (*xb)[8] = (kq < 2) ? bufA : bufB;
    const int kg0 = kq * 128;
    const int koff = (kq < 2) ? kg0 : kg0 - 256;
    #pragma unroll 8
    for (int u = 0; u < 128; ++u) {
      const float v = Ws[(size_t)(kg0 + u) * NSn + jc];
      F4 xa, xb4;
      xa.v = *(const float4*)&xb[koff + u][0];
      xb4.v = *(const float4*)&xb[koff + u][4];
      acc[0] += xa.f[0] * v; acc[1] += xa.f[1] * v;
      acc[2] += xa.f[2] * v; acc[3] += xa.f[3] * v;
      acc[4] += xb4.f[0] * v; acc[5] += xb4.f[1] * v;
      acc[6] += xb4.f[2] * v; acc[7] += xb4.f[3] * v;
    }
  }
  if (kq) {
    #pragma unroll
    for (int i = 0; i < 8; ++i) red[kq - 1][i][jc] = acc[i];
  }
  __syncthreads();
  if (!kq && jc < NSn) {
    #pragma unroll
    for (int i = 0; i < 8; ++i)
      outS[(size_t)(r0 + i) * NSn + jc] =
          acc[i] + red[0][i][jc] + red[1][i][jc] + red[2][i][jc];
  }

  // intent head on blocks 0..15
  if (blk < Bn) {
    const int b = blk;
    if (tid < Sn) aL[tid] = alphas[b * Sn + tid];
    __syncthreads();
    const int h = tid & (Hn - 1);
    const int k2 = tid >> 8;
    float ps = 0.f;
    #pragma unroll 8
    for (int s = k2 * 64; s < k2 * 64 + 64; ++s)
      ps += c_slot[(size_t)(b * Sn + s) * Hn + h] * aL[s];
    ptA[k2][h] = ps;
    __syncthreads();
    if (!k2) {
      cv[h] = c_inte[b * Hn + h] + g2[b * Hn + h] * (ptA[0][h] + ptA[1][h]);
      cv[Hn + h] = hp[(size_t)(b * Sn + Sn - 1) * Hn + h];
    }
    __syncthreads();
    if (tid < NLn * 16) {
      const int l = tid >> 4, c = tid & 15;
      float p = 0.f;
      #pragma unroll
      for (int k = c * 32; k < c * 32 + 32; ++k) p += cv[k] * Wi[k * NLn + l];
      ip[l][c] = p;
    }
    __syncthreads();
    if (tid < NLn) {
      float t = 0.f;
      #pragma unroll
      for (int c = 0; c < 16; ++c) t += ip[tid][c];
      outI[b * NLn + tid] = t;
    }
  }
}

// ---------------------------------------------------------------------------
extern "C" void kernel_launch(void* const* d_in, const int* in_sizes, int n_in,
                              void* d_out, int out_size, void* d_ws, size_t ws_size,
                              hipStream_t stream) {
  const float* hp     = (const float*)d_in[0];
  const float* c_slot = (const float*)d_in[1];
  const float* c_inte = (const float*)d_in[2];
  const float* W_SF   = (const float*)d_in[3];
  const float* V_SF   = (const float*)d_in[4];
  const float* V1     = (const float*)d_in[5];
  const float* V2w    = (const float*)d_in[6];
  const float* V2b    = (const float*)d_in[7];
  const float* wid    = (const float*)d_in[8];
  const float* Wi     = (const float*)d_in[9];
  const float* Ws     = (const float*)d_in[10];
  float* outS = (float*)d_out;                   // B*S*NS
  float* outI = (float*)d_out + Bn * Sn * NSn;   // B*NL

  float* ws = (float*)d_ws;
  float* ZT     = ws;                       // B*H*S (j-contig)
  float* g2     = ZT + (size_t)Bn * Sn * Hn;
  float* alphas = g2 + Bn * Hn;

  // hf + A(it=0) fused
  hipLaunchKernelGGL(k_hfA, dim3(256 + Bn), dim3(1024), 0, stream,
                     hp, V2w, V2b, c_slot, c_inte, W_SF, V_SF, ZT, g2);
  hipLaunchKernelGGL(k_C, dim3(Bn * Sn / 8), dim3(1024), 0, stream,
                     c_slot, V1, g2, ZT, wid, alphas);
  for (int it = 1; it < 3; ++it) {
    hipLaunchKernelGGL(k_A, dim3(Bn), dim3(1024), 0, stream,
                       c_slot, c_inte, W_SF, V_SF, alphas, g2);
    hipLaunchKernelGGL(k_C, dim3(Bn * Sn / 8), dim3(1024), 0, stream,
                       c_slot, V1, g2, ZT, wid, alphas);
  }
  hipLaunchKernelGGL(k_out, dim3(Bn * Sn / 8), dim3(512), 0, stream,
                     hp, c_slot, c_inte, g2, alphas, Wi, Ws, outS, outI);
}